// Round 9
// baseline (284.424 us; speedup 1.0000x reference)
//
#include <hip/hip_runtime.h>
#include <math.h>

#define NB 16
#define NC 64
#define NN 1024
#define NK 9
#define NH 4
#define NF 15

// ---- workspace layout (float offsets) ----
#define OFF_HN     0              /* hnorm [16][64][1024] = 1048576 */
#define OFF_SQV    1048576        /* [16*1024] */
#define OFF_IDX    1064960        /* int[16*1024*9] = 147456 */
#define OFF_DEN1   1212416        /* [4*16*1024] */
#define OFF_U1     1277952        /* [4*16*16] */
#define OFF_DEN2   1278976        /* [16*1024] */
#define OFF_U2     1295360        /* [16*64] */
#define OFF_F11    1296384        /* [4*16*1024] */
#define OFF_F21    1361920
#define OFF_F12    1427456        /* [16*1024] */
#define OFF_F22    1443840
#define OFF_E1     1460224        /* [589824] */
#define OFF_E2     2050048        /* [147456] */
#define OFF_WH1    2197504        /* packed [16][1024][64] = 1048576 */
#define OFF_HCAT   3246080        /* [16*1024*64] */
#define OFF_WH2    4294656        /* [16*1024*64] */
#define OFF_YTIL   5343232        /* [16*1024*64] */
#define ZERO_BASE  OFF_DEN1
#define ZERO_LEN   83968          /* den1+u1+den2+u2, contiguous */

__device__ __forceinline__ unsigned fkey(float x){
  unsigned b = __float_as_uint(x);
  return (b & 0x80000000u) ? ~b : (b | 0x80000000u);   // order-preserving float->uint
}
__device__ __forceinline__ float eluf(float x){ return x > 0.f ? x : expm1f(x); }

// ---------------- K1: zero accumulators + h = x/max(||x||,eps) + Wh (all heads) + f1/f2 ----
__global__ __launch_bounds__(256) void k1_norm_wh(const float* __restrict__ x,
    const float* __restrict__ W_heads, const float* __restrict__ a_heads,
    float* __restrict__ hn, float* __restrict__ sqv, float* __restrict__ Wh1,
    float* __restrict__ f1, float* __restrict__ f2, float* __restrict__ ws){
  int t = blockIdx.x*256 + threadIdx.x;
  if (t < ZERO_LEN) ws[ZERO_BASE + t] = 0.f;
  if (t >= NB*NN) return;                   // only first 64 blocks continue
  int b = t >> 10, n = t & 1023;
  const float* xb = x + b*NC*NN;
  float* hb = hn + b*NC*NN;
  float s = 0.f;
  #pragma unroll
  for (int c = 0; c < NC; c++){ float v = xb[c*NN + n]; s = fmaf(v, v, s); }
  float nrm = fmaxf(sqrtf(s), 1e-12f);
  float wh[NH][NF];
  #pragma unroll
  for (int hh = 0; hh < NH; hh++)
    #pragma unroll
    for (int f = 0; f < NF; f++) wh[hh][f] = 0.f;
  float s2 = 0.f;
  for (int c = 0; c < NC; c++){
    float v = xb[c*NN + n] / nrm;           // true IEEE division, like the reference
    hb[c*NN + n] = v;
    s2 = fmaf(v, v, s2);                    // same fmaf chain order as k2's diag dot
    #pragma unroll
    for (int hh = 0; hh < NH; hh++){
      const float* W = W_heads + (hh*NC + c)*NF;
      #pragma unroll
      for (int f = 0; f < NF; f++) wh[hh][f] = fmaf(v, W[f], wh[hh][f]);
    }
  }
  sqv[t] = s2;
  float* orow = Wh1 + ((size_t)(b*NN) + n)*64;
  #pragma unroll
  for (int hh = 0; hh < NH; hh++){
    const float* al = a_heads + hh*2*NF;
    float s1 = 0.f, sb = 0.f;
    #pragma unroll
    for (int f = 0; f < NF; f++){ s1 = fmaf(wh[hh][f], al[f], s1); sb = fmaf(wh[hh][f], al[NF+f], sb); }
    float4* o4 = (float4*)(orow + hh*16);
    o4[0] = make_float4(wh[hh][0], wh[hh][1], wh[hh][2], wh[hh][3]);
    o4[1] = make_float4(wh[hh][4], wh[hh][5], wh[hh][6], wh[hh][7]);
    o4[2] = make_float4(wh[hh][8], wh[hh][9], wh[hh][10], wh[hh][11]);
    o4[3] = make_float4(wh[hh][12], wh[hh][13], wh[hh][14], 0.f);
    int hb2 = hh*NB + b;
    f1[hb2*NN + n] = s1; f2[hb2*NN + n] = sb;
  }
}

// ---------------- K2: fused KNN (dist GEMM in LDS + exact top-9 + edges + den1) ----------------
// block = (i-panel of 64 rows, batch b); 256 threads; never materializes dist in global.
#define LSTR 68   /* LDS row stride: 272B -> float4-aligned for any row */
__global__ __launch_bounds__(256) void k2_knn(const float* __restrict__ hn,
    const float* __restrict__ sqv, const float* __restrict__ f1g, const float* __restrict__ f2g,
    int* __restrict__ idxb, float* __restrict__ e1, float* __restrict__ den1){
  __shared__ float As[64][LSTR];
  __shared__ float Bs[64][LSTR];
  __shared__ float Ds[64][LSTR];
  __shared__ float ssq[64], sjq[64];
  int b  = blockIdx.y;
  int i0 = blockIdx.x * 64;
  int tid = threadIdx.x;
  const float* hb = hn + b*NC*NN;
  // stage A-panel (c-major) + row sq-norms
  #pragma unroll
  for (int k = 0; k < 4; k++){
    int idx4 = tid + k*256;                 // 0..1023
    int c = idx4 >> 4, q4 = (idx4 & 15) * 4;
    *(float4*)&As[c][q4] = *(const float4*)&hb[c*NN + i0 + q4];
  }
  if (tid < 64) ssq[tid] = sqv[b*NN + i0 + tid];
  int rg = tid >> 4, cg = tid & 15;         // GEMM: rows rg*4.., cols cg*4..
  int r  = tid >> 2, p  = tid & 3;          // selection: row r, col-stripe p
  unsigned long long s0=~0ull,s1=~0ull,s2k=~0ull,s3=~0ull,s4=~0ull,s5=~0ull,s6=~0ull,s7=~0ull,s8=~0ull;
  for (int jt = 0; jt < 16; jt++){
    int j0 = jt * 64;
    __syncthreads();                        // prev selection done; safe to restage Bs
    #pragma unroll
    for (int k = 0; k < 4; k++){
      int idx4 = tid + k*256;
      int c = idx4 >> 4, q4 = (idx4 & 15) * 4;
      *(float4*)&Bs[c][q4] = *(const float4*)&hb[c*NN + j0 + q4];
    }
    if (tid < 64) sjq[tid] = sqv[b*NN + j0 + tid];
    __syncthreads();
    float acc[4][4];
    #pragma unroll
    for (int q = 0; q < 4; q++)
      #pragma unroll
      for (int jj = 0; jj < 4; jj++) acc[q][jj] = 0.f;
    #pragma unroll 4
    for (int c = 0; c < 64; c++){
      float4 a  = *(const float4*)&As[c][rg*4];
      float4 bb = *(const float4*)&Bs[c][cg*4];
      float av[4] = {a.x, a.y, a.z, a.w};
      float bv[4] = {bb.x, bb.y, bb.z, bb.w};
      #pragma unroll
      for (int q = 0; q < 4; q++)
        #pragma unroll
        for (int jj = 0; jj < 4; jj++) acc[q][jj] = fmaf(av[q], bv[jj], acc[q][jj]);
    }
    #pragma unroll
    for (int q = 0; q < 4; q++){
      float si = ssq[rg*4+q];
      float4 o;
      o.x = (si - 2.f*acc[q][0]) + sjq[cg*4+0];   // exact +0 on diagonal
      o.y = (si - 2.f*acc[q][1]) + sjq[cg*4+1];
      o.z = (si - 2.f*acc[q][2]) + sjq[cg*4+2];
      o.w = (si - 2.f*acc[q][3]) + sjq[cg*4+3];
      *(float4*)&Ds[rg*4+q][cg*4] = o;
    }
    __syncthreads();
    // selection scan: thread (r,p) scans cols p*16..p*16+15 of row r
    #pragma unroll
    for (int m = 0; m < 4; m++){
      float4 v = *(const float4*)&Ds[r][p*16 + m*4];
      float vv[4] = {v.x, v.y, v.z, v.w};
      #pragma unroll
      for (int q = 0; q < 4; q++){
        unsigned long long kk = ((unsigned long long)fkey(vv[q]) << 32)
                              | (unsigned)(j0 + p*16 + m*4 + q);
        if (kk < s8){                       // gated insertion into sorted-9 (static indices)
          s8 = kk;
          unsigned long long tt;
          if (s8 < s7){ tt=s7; s7=s8; s8=tt; }
          if (s7 < s6){ tt=s6; s6=s7; s7=tt; }
          if (s6 < s5){ tt=s5; s5=s6; s6=tt; }
          if (s5 < s4){ tt=s4; s4=s5; s5=tt; }
          if (s4 < s3){ tt=s3; s3=s4; s4=tt; }
          if (s3 < s2k){ tt=s2k; s2k=s3; s3=tt; }
          if (s2k < s1){ tt=s1; s1=s2k; s2k=tt; }
          if (s1 < s0){ tt=s0; s0=s1; s1=tt; }
        }
      }
    }
  }
  // merge 4 sorted lists per row (lanes r*4+p, p=0..3) + fused epilogue
  int i = i0 + r;
  int hbh = p*NB + b;                       // head p
  float f1v = f1g[hbh*NN + i];
  unsigned long long h = s0;
  #pragma unroll
  for (int round = 0; round < NK; round++){
    unsigned long long g = h;
    unsigned long long o1 = __shfl_xor(g, 1); g = o1 < g ? o1 : g;
    unsigned long long o2 = __shfl_xor(g, 2); g = o2 < g ? o2 : g;
    if (h == g){                            // unique winner (keys distinct): pop head
      s0=s1; s1=s2k; s2k=s3; s3=s4; s4=s5; s5=s6; s6=s7; s7=s8; s8=~0ull; h=s0;
    }
    int j = (int)(g & 0xFFFFFFFFu);
    if (p == 0) idxb[((size_t)(b*NN) + i)*NK + round] = j;
    float e = f1v + f2g[hbh*NN + j];
    e = e >= 0.f ? e : 0.2f*e;
    e1[((size_t)(hbh*NN) + i)*NK + round] = e;
    atomicAdd(den1 + hbh*NN + j, expf(e));
  }
}

// ---------------- K4b: empty-column uniform correction (layer 1) ----------------
__global__ __launch_bounds__(256) void k4b_u1(const float* __restrict__ denom1,
                       const float* __restrict__ Wh1, float* __restrict__ u1){
  int t = blockIdx.x*256 + threadIdx.x;    // hb*NN + j
  if (denom1[t] != 0.f) return;
  int hb = t >> 10, j = t & 1023;
  int hh = hb >> 4, b = hb & 15;
  const float* w = Wh1 + ((size_t)(b*NN) + j)*64 + hh*16;
  for (int f = 0; f < NF; f++) atomicAdd(u1 + hb*16 + f, w[f] * (1.f/1024.f));
}

// ---------------- K5: hp1 = att @ Wh (wave-per-row, lane=(head,f)) ----------------
__global__ __launch_bounds__(256) void k5_hp1(const int* __restrict__ idxb, const float* __restrict__ e1,
    const float* __restrict__ denom1, const float* __restrict__ Wh1,
    const float* __restrict__ u1, float* __restrict__ hcat){
  int wave = threadIdx.x >> 6, lane = threadIdx.x & 63;
  int t = blockIdx.x*4 + wave;             // b*NN + i
  int b = t >> 10, i = t & 1023;
  int hh = lane >> 4, f = lane & 15;
  int hb = hh*NB + b;
  float acc = u1[hb*16 + f];               // slot 15 is zeroed
  const int* jp = idxb + (size_t)t*NK;
  const float* ep = e1 + (size_t)(hb*NN + i)*NK;
  const float* dn = denom1 + hb*NN;
  const float* wbase = Wh1 + ((size_t)(b*NN))*64;
  #pragma unroll 3
  for (int k = 0; k < NK; k++){
    int j = jp[k];
    float att = expf(ep[k]) / dn[j];
    acc = fmaf(att, wbase[(size_t)j*64 + lane], acc);
  }
  if (f < NF) hcat[((size_t)(b*NN) + i)*64 + hh*NF + f] = eluf(acc);
}

// ---------------- K7: Wh2 = hcat @ W_out + f1/f2 ----------------
__global__ __launch_bounds__(256) void k7_wh2(const float* __restrict__ hcat,
    const float* __restrict__ W_out, const float* __restrict__ a_out,
    float* __restrict__ Wh2, float* __restrict__ f1, float* __restrict__ f2){
  __shared__ float hcl[64][65];
  __shared__ float p1[4][64], p2[4][64];
  int b = blockIdx.y, n0 = blockIdx.x*64;
  for (int t = threadIdx.x; t < 4096; t += 256){
    int nl = t >> 6, c = t & 63;
    hcl[nl][c] = hcat[(size_t)((b*NN) + n0 + nl)*64 + c];
  }
  __syncthreads();
  int nl = threadIdx.x & 63;
  int wv = threadIdx.x >> 6;
  int og = __builtin_amdgcn_readfirstlane(wv * 16);
  float z[16];
  #pragma unroll
  for (int m = 0; m < 16; m++) z[m] = 0.f;
  for (int c = 0; c < 60; c++){
    float yv = hcl[nl][c];
    #pragma unroll
    for (int m = 0; m < 16; m++) z[m] = fmaf(yv, W_out[c*64 + og + m], z[m]);
  }
  int n = n0 + nl;
  float* o = Wh2 + ((size_t)(b*NN) + n)*64 + og;
  #pragma unroll
  for (int m = 0; m < 16; m += 4) *(float4*)&o[m] = make_float4(z[m],z[m+1],z[m+2],z[m+3]);
  float s1 = 0.f, s2 = 0.f;
  #pragma unroll
  for (int m = 0; m < 16; m++){ s1 = fmaf(z[m], a_out[og+m], s1); s2 = fmaf(z[m], a_out[64+og+m], s2); }
  p1[wv][nl] = s1; p2[wv][nl] = s2;
  __syncthreads();
  if (threadIdx.x < 64){
    f1[b*NN + n0 + threadIdx.x] = p1[0][threadIdx.x] + p1[1][threadIdx.x] + p1[2][threadIdx.x] + p1[3][threadIdx.x];
    f2[b*NN + n0 + threadIdx.x] = p2[0][threadIdx.x] + p2[1][threadIdx.x] + p2[2][threadIdx.x] + p2[3][threadIdx.x];
  }
}

// ---------------- K8: layer-2 edges + denominators ----------------
__global__ __launch_bounds__(256) void k8_edge2(const int* __restrict__ idxb, const float* __restrict__ f1,
                         const float* __restrict__ f2, float* __restrict__ e2,
                         float* __restrict__ denom2){
  int t = blockIdx.x*256 + threadIdx.x;    // (b*NN + i)*9 + k
  int bi = t / 9;
  int b = bi >> 10;
  int j = idxb[t];
  float e = f1[bi] + f2[b*NN + j];
  e = e >= 0.f ? e : 0.2f*e;
  e2[t] = e;
  atomicAdd(denom2 + b*NN + j, expf(e));
}

// ---------------- K8b: empty-column correction (layer 2) ----------------
__global__ __launch_bounds__(256) void k8b_u2(const float* __restrict__ denom2,
                       const float* __restrict__ Wh2, float* __restrict__ u2){
  int t = blockIdx.x*256 + threadIdx.x;    // b*NN + j
  if (denom2[t] != 0.f) return;
  int b = t >> 10;
  const float* w = Wh2 + (size_t)t*64;
  for (int f = 0; f < 64; f++) atomicAdd(u2 + b*64 + f, w[f] * (1.f/1024.f));
}

// ---------------- K9: hp2 -> elu -> leaky(0.01) (wave-per-row, lane=channel) ----------------
__global__ __launch_bounds__(256) void k9_hp2(const int* __restrict__ idxb, const float* __restrict__ e2,
    const float* __restrict__ denom2, const float* __restrict__ Wh2,
    const float* __restrict__ u2, float* __restrict__ ytil){
  int wave = threadIdx.x >> 6, lane = threadIdx.x & 63;
  int t = blockIdx.x*4 + wave;             // b*NN + i
  int b = t >> 10;
  float acc = u2[b*64 + lane];
  const int* jp = idxb + (size_t)t*NK;
  const float* ep = e2 + (size_t)t*NK;
  const float* dn = denom2 + b*NN;
  const float* wbase = Wh2 + ((size_t)(b*NN))*64;
  #pragma unroll 3
  for (int k = 0; k < NK; k++){
    int j = jp[k];
    float att = expf(ep[k]) / dn[j];
    acc = fmaf(att, wbase[(size_t)j*64 + lane], acc);
  }
  float v = eluf(acc);
  ytil[(size_t)t*64 + lane] = v >= 0.f ? v : 0.01f*v;
}

// ---------------- K11: 1x1 conv + BN + residual ----------------
__global__ __launch_bounds__(256) void k11_conv(const float* __restrict__ ytil,
    const float* __restrict__ conv_w, const float* __restrict__ conv_b,
    const float* __restrict__ bn_g, const float* __restrict__ bn_b,
    const float* __restrict__ x, float* __restrict__ out){
  __shared__ float yt[64][65];
  int b = blockIdx.y, n0 = blockIdx.x*64;
  for (int t = threadIdx.x; t < 4096; t += 256){
    int nl = t >> 6, c = t & 63;
    yt[nl][c] = ytil[(size_t)((b*NN) + n0 + nl)*64 + c];
  }
  __syncthreads();
  int nl = threadIdx.x & 63;
  int og = __builtin_amdgcn_readfirstlane((int)(threadIdx.x >> 6) * 16);
  float z[16];
  #pragma unroll
  for (int m = 0; m < 16; m++) z[m] = 0.f;
  for (int c = 0; c < 64; c++){
    float yv = yt[nl][c];
    #pragma unroll
    for (int m = 0; m < 16; m++) z[m] = fmaf(yv, conv_w[(og+m)*64 + c], z[m]);
  }
  const float scbn = 1.f / sqrtf(1.f + 1e-5f);
  #pragma unroll
  for (int m = 0; m < 16; m++){
    int o = og + m;
    size_t oi = ((size_t)(b*64 + o))*NN + n0 + nl;
    out[oi] = fmaf(z[m] + conv_b[o], bn_g[o]*scbn, bn_b[o]) + x[oi];
  }
}

extern "C" void kernel_launch(void* const* d_in, const int* in_sizes, int n_in,
                              void* d_out, int out_size, void* d_ws, size_t ws_size,
                              hipStream_t stream){
  (void)in_sizes; (void)n_in; (void)out_size; (void)ws_size;
  const float* x       = (const float*)d_in[0];
  const float* W_heads = (const float*)d_in[1];
  const float* a_heads = (const float*)d_in[2];
  const float* W_out   = (const float*)d_in[3];
  const float* a_out   = (const float*)d_in[4];
  const float* conv_w  = (const float*)d_in[5];
  const float* conv_b  = (const float*)d_in[6];
  const float* bn_g    = (const float*)d_in[7];
  const float* bn_b    = (const float*)d_in[8];
  float* ws  = (float*)d_ws;
  float* out = (float*)d_out;

  float* hn   = ws + OFF_HN;
  float* sqv  = ws + OFF_SQV;
  int*   idxb = (int*)(ws + OFF_IDX);
  float* den1 = ws + OFF_DEN1;
  float* u1   = ws + OFF_U1;
  float* den2 = ws + OFF_DEN2;
  float* u2   = ws + OFF_U2;
  float* f11  = ws + OFF_F11;
  float* f21  = ws + OFF_F21;
  float* f12  = ws + OFF_F12;
  float* f22  = ws + OFF_F22;
  float* e1   = ws + OFF_E1;
  float* e2   = ws + OFF_E2;
  float* Wh1  = ws + OFF_WH1;
  float* hcat = ws + OFF_HCAT;
  float* Wh2  = ws + OFF_WH2;
  float* ytil = ws + OFF_YTIL;

  k1_norm_wh<<<dim3(328), dim3(256), 0, stream>>>(x, W_heads, a_heads, hn, sqv, Wh1, f11, f21, ws);
  k2_knn<<<dim3(16,16), dim3(256), 0, stream>>>(hn, sqv, f11, f21, idxb, e1, den1);
  k4b_u1<<<dim3(256), dim3(256), 0, stream>>>(den1, Wh1, u1);
  k5_hp1<<<dim3(4096), dim3(256), 0, stream>>>(idxb, e1, den1, Wh1, u1, hcat);
  k7_wh2<<<dim3(16,16), dim3(256), 0, stream>>>(hcat, W_out, a_out, Wh2, f12, f22);
  k8_edge2<<<dim3(576), dim3(256), 0, stream>>>(idxb, f12, f22, e2, den2);
  k8b_u2<<<dim3(64), dim3(256), 0, stream>>>(den2, Wh2, u2);
  k9_hp2<<<dim3(4096), dim3(256), 0, stream>>>(idxb, e2, den2, Wh2, u2, ytil);
  k11_conv<<<dim3(16,16), dim3(256), 0, stream>>>(ytil, conv_w, conv_b, bn_g, bn_b, x, out);
}

// Round 10
// 262.866 us; speedup vs baseline: 1.0820x; 1.0820x over previous
//
#include <hip/hip_runtime.h>
#include <math.h>

#define NB 16
#define NC 64
#define NN 1024
#define NK 9
#define NH 4
#define NF 15

// ---- workspace layout (float offsets) ----
#define OFF_HN     0              /* hnorm [16][64][1024] = 1048576 */
#define OFF_SQV    1048576        /* [16*1024] */
#define OFF_IDX    1064960        /* int[16*1024*9] = 147456 */
#define OFF_DEN1   1212416        /* [4*16*1024] */
#define OFF_U1     1277952        /* [4*16*16] */
#define OFF_DEN2   1278976        /* [16*1024] */
#define OFF_U2     1295360        /* [16*64] */
#define OFF_F11    1296384        /* [4*16*1024] */
#define OFF_F21    1361920
#define OFF_F12    1427456        /* [16*1024] */
#define OFF_F22    1443840
#define OFF_E1     1460224        /* [589824] */
#define OFF_E2     2050048        /* [147456] */
#define OFF_WH1    2197504        /* packed [16][1024][64] = 1048576 */
#define OFF_HCAT   3246080        /* [16*1024*64] */
#define OFF_WH2    4294656        /* [16*1024*64] */
#define OFF_YTIL   5343232        /* [16*1024*64] */
#define OFF_CAND   6391808        /* u64[16*1024*36] = 1179648 floats */
#define ZERO_BASE  OFF_DEN1
#define ZERO_LEN   83968          /* den1+u1+den2+u2, contiguous */

__device__ __forceinline__ unsigned fkey(float x){
  unsigned b = __float_as_uint(x);
  return (b & 0x80000000u) ? ~b : (b | 0x80000000u);   // order-preserving float->uint
}
__device__ __forceinline__ float eluf(float x){ return x > 0.f ? x : expm1f(x); }

// ---------------- K1: zero accumulators + h = x/max(||x||,eps) + Wh (all heads) + f1/f2 ----
__global__ __launch_bounds__(256) void k1_norm_wh(const float* __restrict__ x,
    const float* __restrict__ W_heads, const float* __restrict__ a_heads,
    float* __restrict__ hn, float* __restrict__ sqv, float* __restrict__ Wh1,
    float* __restrict__ f1, float* __restrict__ f2, float* __restrict__ ws){
  int t = blockIdx.x*256 + threadIdx.x;
  if (t < ZERO_LEN) ws[ZERO_BASE + t] = 0.f;
  if (t >= NB*NN) return;                   // only first 64 blocks continue
  int b = t >> 10, n = t & 1023;
  const float* xb = x + b*NC*NN;
  float* hb = hn + b*NC*NN;
  float s = 0.f;
  #pragma unroll
  for (int c = 0; c < NC; c++){ float v = xb[c*NN + n]; s = fmaf(v, v, s); }
  float nrm = fmaxf(sqrtf(s), 1e-12f);
  float wh[NH][NF];
  #pragma unroll
  for (int hh = 0; hh < NH; hh++)
    #pragma unroll
    for (int f = 0; f < NF; f++) wh[hh][f] = 0.f;
  float s2 = 0.f;
  for (int c = 0; c < NC; c++){
    float v = xb[c*NN + n] / nrm;           // true IEEE division, like the reference
    hb[c*NN + n] = v;
    s2 = fmaf(v, v, s2);                    // same fmaf chain order as k2's diag dot
    #pragma unroll
    for (int hh = 0; hh < NH; hh++){
      const float* W = W_heads + (hh*NC + c)*NF;
      #pragma unroll
      for (int f = 0; f < NF; f++) wh[hh][f] = fmaf(v, W[f], wh[hh][f]);
    }
  }
  sqv[t] = s2;
  float* orow = Wh1 + ((size_t)(b*NN) + n)*64;
  #pragma unroll
  for (int hh = 0; hh < NH; hh++){
    const float* al = a_heads + hh*2*NF;
    float s1 = 0.f, sb = 0.f;
    #pragma unroll
    for (int f = 0; f < NF; f++){ s1 = fmaf(wh[hh][f], al[f], s1); sb = fmaf(wh[hh][f], al[NF+f], sb); }
    float4* o4 = (float4*)(orow + hh*16);
    o4[0] = make_float4(wh[hh][0], wh[hh][1], wh[hh][2], wh[hh][3]);
    o4[1] = make_float4(wh[hh][4], wh[hh][5], wh[hh][6], wh[hh][7]);
    o4[2] = make_float4(wh[hh][8], wh[hh][9], wh[hh][10], wh[hh][11]);
    o4[3] = make_float4(wh[hh][12], wh[hh][13], wh[hh][14], 0.f);
    int hb2 = hh*NB + b;
    f1[hb2*NN + n] = s1; f2[hb2*NN + n] = sb;
  }
}

// ---------------- K2a: KNN candidates per (64-row panel, 256-col quarter) ----------------
// grid (16,16,4) = 1024 blocks -> 3 blocks/CU (LDS 52.7KB). dist never hits global.
#define LSTR 68   /* LDS row stride: 272B -> float4-aligned for any row */
__global__ __launch_bounds__(256) void k2cand(const float* __restrict__ hn,
    const float* __restrict__ sqv, unsigned long long* __restrict__ cand){
  __shared__ float As[64][LSTR];
  __shared__ float Bs[64][LSTR];
  __shared__ float Ds[64][LSTR];
  __shared__ float ssq[64], sjq[64];
  int i0 = blockIdx.x * 64;
  int b  = blockIdx.y;
  int jq = blockIdx.z;                      // quarter: j in [jq*256, jq*256+256)
  int tid = threadIdx.x;
  const float* hb = hn + b*NC*NN;
  #pragma unroll
  for (int k = 0; k < 4; k++){
    int idx4 = tid + k*256;                 // 0..1023
    int c = idx4 >> 4, q4 = (idx4 & 15) * 4;
    *(float4*)&As[c][q4] = *(const float4*)&hb[c*NN + i0 + q4];
  }
  if (tid < 64) ssq[tid] = sqv[b*NN + i0 + tid];
  int rg = tid >> 4, cg = tid & 15;         // GEMM: rows rg*4.., cols cg*4..
  int r  = tid >> 2, p  = tid & 3;          // selection: row r, col-stripe p
  unsigned long long s0=~0ull,s1=~0ull,s2k=~0ull,s3=~0ull,s4=~0ull,s5=~0ull,s6=~0ull,s7=~0ull,s8=~0ull;
  for (int jst = 0; jst < 4; jst++){
    int j0 = jq*256 + jst*64;
    __syncthreads();                        // prev selection done; safe to restage Bs
    #pragma unroll
    for (int k = 0; k < 4; k++){
      int idx4 = tid + k*256;
      int c = idx4 >> 4, q4 = (idx4 & 15) * 4;
      *(float4*)&Bs[c][q4] = *(const float4*)&hb[c*NN + j0 + q4];
    }
    if (tid < 64) sjq[tid] = sqv[b*NN + j0 + tid];
    __syncthreads();
    float acc[4][4];
    #pragma unroll
    for (int q = 0; q < 4; q++)
      #pragma unroll
      for (int jj = 0; jj < 4; jj++) acc[q][jj] = 0.f;
    #pragma unroll 4
    for (int c = 0; c < 64; c++){
      float4 a  = *(const float4*)&As[c][rg*4];
      float4 bb = *(const float4*)&Bs[c][cg*4];
      float av[4] = {a.x, a.y, a.z, a.w};
      float bv[4] = {bb.x, bb.y, bb.z, bb.w};
      #pragma unroll
      for (int q = 0; q < 4; q++)
        #pragma unroll
        for (int jj = 0; jj < 4; jj++) acc[q][jj] = fmaf(av[q], bv[jj], acc[q][jj]);
    }
    #pragma unroll
    for (int q = 0; q < 4; q++){
      float si = ssq[rg*4+q];
      float4 o;
      o.x = (si - 2.f*acc[q][0]) + sjq[cg*4+0];   // exact +0 on diagonal
      o.y = (si - 2.f*acc[q][1]) + sjq[cg*4+1];
      o.z = (si - 2.f*acc[q][2]) + sjq[cg*4+2];
      o.w = (si - 2.f*acc[q][3]) + sjq[cg*4+3];
      *(float4*)&Ds[rg*4+q][cg*4] = o;
    }
    __syncthreads();
    // selection scan: thread (r,p) scans cols p*16..p*16+15 of row r
    #pragma unroll
    for (int m = 0; m < 4; m++){
      float4 v = *(const float4*)&Ds[r][p*16 + m*4];
      float vv[4] = {v.x, v.y, v.z, v.w};
      #pragma unroll
      for (int q = 0; q < 4; q++){
        unsigned long long kk = ((unsigned long long)fkey(vv[q]) << 32)
                              | (unsigned)(j0 + p*16 + m*4 + q);
        if (kk < s8){                       // gated insertion into sorted-9 (static indices)
          s8 = kk;
          unsigned long long tt;
          if (s8 < s7){ tt=s7; s7=s8; s8=tt; }
          if (s7 < s6){ tt=s6; s6=s7; s7=tt; }
          if (s6 < s5){ tt=s5; s5=s6; s6=tt; }
          if (s5 < s4){ tt=s4; s4=s5; s5=tt; }
          if (s4 < s3){ tt=s3; s3=s4; s4=tt; }
          if (s3 < s2k){ tt=s2k; s2k=s3; s3=tt; }
          if (s2k < s1){ tt=s1; s1=s2k; s2k=tt; }
          if (s1 < s0){ tt=s0; s0=s1; s1=tt; }
        }
      }
    }
  }
  // merge 4 sorted lists per row (lanes r*4+p, p=0..3) -> per-quarter top-9
  int i = i0 + r;
  unsigned long long* cp = cand + ((size_t)(b*NN) + i)*36 + jq*9;
  unsigned long long h = s0;
  #pragma unroll
  for (int round = 0; round < NK; round++){
    unsigned long long g = h;
    unsigned long long o1 = __shfl_xor(g, 1); g = o1 < g ? o1 : g;
    unsigned long long o2 = __shfl_xor(g, 2); g = o2 < g ? o2 : g;
    if (h == g){                            // unique winner (keys distinct): pop head
      s0=s1; s1=s2k; s2k=s3; s3=s4; s4=s5; s5=s6; s6=s7; s7=s8; s8=~0ull; h=s0;
    }
    if (p == 0) cp[round] = g;
  }
}

// ---------------- K2b: merge 36 candidates -> exact top-9 + edges + den1 ----------------
__global__ __launch_bounds__(256) void k2merge(const unsigned long long* __restrict__ cand,
    const float* __restrict__ f1g, const float* __restrict__ f2g,
    int* __restrict__ idxb, float* __restrict__ e1, float* __restrict__ den1){
  int t = blockIdx.x*256 + threadIdx.x;     // b*NN + i
  int b = t >> 10, i = t & 1023;
  const unsigned long long* cp = cand + (size_t)t*36;
  unsigned long long s0=~0ull,s1=~0ull,s2k=~0ull,s3=~0ull,s4=~0ull,s5=~0ull,s6=~0ull,s7=~0ull,s8=~0ull;
  #pragma unroll
  for (int m = 0; m < 36; m++){
    unsigned long long kk = cp[m];
    if (kk < s8){
      s8 = kk;
      unsigned long long tt;
      if (s8 < s7){ tt=s7; s7=s8; s8=tt; }
      if (s7 < s6){ tt=s6; s6=s7; s7=tt; }
      if (s6 < s5){ tt=s5; s5=s6; s6=tt; }
      if (s5 < s4){ tt=s4; s4=s5; s5=tt; }
      if (s4 < s3){ tt=s3; s3=s4; s4=tt; }
      if (s3 < s2k){ tt=s2k; s2k=s3; s3=tt; }
      if (s2k < s1){ tt=s1; s1=s2k; s2k=tt; }
      if (s1 < s0){ tt=s0; s0=s1; s1=tt; }
    }
  }
  int jj[NK];
  jj[0]=(int)(s0&0xFFFFFFFFu); jj[1]=(int)(s1&0xFFFFFFFFu); jj[2]=(int)(s2k&0xFFFFFFFFu);
  jj[3]=(int)(s3&0xFFFFFFFFu); jj[4]=(int)(s4&0xFFFFFFFFu); jj[5]=(int)(s5&0xFFFFFFFFu);
  jj[6]=(int)(s6&0xFFFFFFFFu); jj[7]=(int)(s7&0xFFFFFFFFu); jj[8]=(int)(s8&0xFFFFFFFFu);
  int* op = idxb + (size_t)t*NK;
  #pragma unroll
  for (int k = 0; k < NK; k++) op[k] = jj[k];
  #pragma unroll
  for (int hh = 0; hh < NH; hh++){
    int hb = hh*NB + b;
    float f1v = f1g[hb*NN + i];
    float* ep = e1 + ((size_t)(hb*NN) + i)*NK;
    #pragma unroll
    for (int k = 0; k < NK; k++){
      int j = jj[k];
      float e = f1v + f2g[hb*NN + j];
      e = e >= 0.f ? e : 0.2f*e;
      ep[k] = e;
      atomicAdd(den1 + hb*NN + j, expf(e));
    }
  }
}

// ---------------- K4b: empty-column uniform correction (layer 1) ----------------
__global__ __launch_bounds__(256) void k4b_u1(const float* __restrict__ denom1,
                       const float* __restrict__ Wh1, float* __restrict__ u1){
  int t = blockIdx.x*256 + threadIdx.x;    // hb*NN + j
  if (denom1[t] != 0.f) return;
  int hb = t >> 10, j = t & 1023;
  int hh = hb >> 4, b = hb & 15;
  const float* w = Wh1 + ((size_t)(b*NN) + j)*64 + hh*16;
  for (int f = 0; f < NF; f++) atomicAdd(u1 + hb*16 + f, w[f] * (1.f/1024.f));
}

// ---------------- K5: hp1 = att @ Wh (wave-per-row, lane=(head,f)) ----------------
__global__ __launch_bounds__(256) void k5_hp1(const int* __restrict__ idxb, const float* __restrict__ e1,
    const float* __restrict__ denom1, const float* __restrict__ Wh1,
    const float* __restrict__ u1, float* __restrict__ hcat){
  int wave = threadIdx.x >> 6, lane = threadIdx.x & 63;
  int t = blockIdx.x*4 + wave;             // b*NN + i
  int b = t >> 10, i = t & 1023;
  int hh = lane >> 4, f = lane & 15;
  int hb = hh*NB + b;
  float acc = u1[hb*16 + f];               // slot 15 is zeroed
  const int* jp = idxb + (size_t)t*NK;
  const float* ep = e1 + (size_t)(hb*NN + i)*NK;
  const float* dn = denom1 + hb*NN;
  const float* wbase = Wh1 + ((size_t)(b*NN))*64;
  #pragma unroll 3
  for (int k = 0; k < NK; k++){
    int j = jp[k];
    float att = expf(ep[k]) / dn[j];
    acc = fmaf(att, wbase[(size_t)j*64 + lane], acc);
  }
  if (f < NF) hcat[((size_t)(b*NN) + i)*64 + hh*NF + f] = eluf(acc);
}

// ---------------- K7: Wh2 = hcat @ W_out + f1/f2 ----------------
__global__ __launch_bounds__(256) void k7_wh2(const float* __restrict__ hcat,
    const float* __restrict__ W_out, const float* __restrict__ a_out,
    float* __restrict__ Wh2, float* __restrict__ f1, float* __restrict__ f2){
  __shared__ float hcl[64][65];
  __shared__ float p1[4][64], p2[4][64];
  int b = blockIdx.y, n0 = blockIdx.x*64;
  for (int t = threadIdx.x; t < 4096; t += 256){
    int nl = t >> 6, c = t & 63;
    hcl[nl][c] = hcat[(size_t)((b*NN) + n0 + nl)*64 + c];
  }
  __syncthreads();
  int nl = threadIdx.x & 63;
  int wv = threadIdx.x >> 6;
  int og = __builtin_amdgcn_readfirstlane(wv * 16);
  float z[16];
  #pragma unroll
  for (int m = 0; m < 16; m++) z[m] = 0.f;
  for (int c = 0; c < 60; c++){
    float yv = hcl[nl][c];
    #pragma unroll
    for (int m = 0; m < 16; m++) z[m] = fmaf(yv, W_out[c*64 + og + m], z[m]);
  }
  int n = n0 + nl;
  float* o = Wh2 + ((size_t)(b*NN) + n)*64 + og;
  #pragma unroll
  for (int m = 0; m < 16; m += 4) *(float4*)&o[m] = make_float4(z[m],z[m+1],z[m+2],z[m+3]);
  float s1 = 0.f, s2 = 0.f;
  #pragma unroll
  for (int m = 0; m < 16; m++){ s1 = fmaf(z[m], a_out[og+m], s1); s2 = fmaf(z[m], a_out[64+og+m], s2); }
  p1[wv][nl] = s1; p2[wv][nl] = s2;
  __syncthreads();
  if (threadIdx.x < 64){
    f1[b*NN + n0 + threadIdx.x] = p1[0][threadIdx.x] + p1[1][threadIdx.x] + p1[2][threadIdx.x] + p1[3][threadIdx.x];
    f2[b*NN + n0 + threadIdx.x] = p2[0][threadIdx.x] + p2[1][threadIdx.x] + p2[2][threadIdx.x] + p2[3][threadIdx.x];
  }
}

// ---------------- K8: layer-2 edges + denominators ----------------
__global__ __launch_bounds__(256) void k8_edge2(const int* __restrict__ idxb, const float* __restrict__ f1,
                         const float* __restrict__ f2, float* __restrict__ e2,
                         float* __restrict__ denom2){
  int t = blockIdx.x*256 + threadIdx.x;    // (b*NN + i)*9 + k
  int bi = t / 9;
  int b = bi >> 10;
  int j = idxb[t];
  float e = f1[bi] + f2[b*NN + j];
  e = e >= 0.f ? e : 0.2f*e;
  e2[t] = e;
  atomicAdd(denom2 + b*NN + j, expf(e));
}

// ---------------- K8b: empty-column correction (layer 2) ----------------
__global__ __launch_bounds__(256) void k8b_u2(const float* __restrict__ denom2,
                       const float* __restrict__ Wh2, float* __restrict__ u2){
  int t = blockIdx.x*256 + threadIdx.x;    // b*NN + j
  if (denom2[t] != 0.f) return;
  int b = t >> 10;
  const float* w = Wh2 + (size_t)t*64;
  for (int f = 0; f < 64; f++) atomicAdd(u2 + b*64 + f, w[f] * (1.f/1024.f));
}

// ---------------- K9: hp2 -> elu -> leaky(0.01) (wave-per-row, lane=channel) ----------------
__global__ __launch_bounds__(256) void k9_hp2(const int* __restrict__ idxb, const float* __restrict__ e2,
    const float* __restrict__ denom2, const float* __restrict__ Wh2,
    const float* __restrict__ u2, float* __restrict__ ytil){
  int wave = threadIdx.x >> 6, lane = threadIdx.x & 63;
  int t = blockIdx.x*4 + wave;             // b*NN + i
  int b = t >> 10;
  float acc = u2[b*64 + lane];
  const int* jp = idxb + (size_t)t*NK;
  const float* ep = e2 + (size_t)t*NK;
  const float* dn = denom2 + b*NN;
  const float* wbase = Wh2 + ((size_t)(b*NN))*64;
  #pragma unroll 3
  for (int k = 0; k < NK; k++){
    int j = jp[k];
    float att = expf(ep[k]) / dn[j];
    acc = fmaf(att, wbase[(size_t)j*64 + lane], acc);
  }
  float v = eluf(acc);
  ytil[(size_t)t*64 + lane] = v >= 0.f ? v : 0.01f*v;
}

// ---------------- K11: 1x1 conv + BN + residual ----------------
__global__ __launch_bounds__(256) void k11_conv(const float* __restrict__ ytil,
    const float* __restrict__ conv_w, const float* __restrict__ conv_b,
    const float* __restrict__ bn_g, const float* __restrict__ bn_b,
    const float* __restrict__ x, float* __restrict__ out){
  __shared__ float yt[64][65];
  int b = blockIdx.y, n0 = blockIdx.x*64;
  for (int t = threadIdx.x; t < 4096; t += 256){
    int nl = t >> 6, c = t & 63;
    yt[nl][c] = ytil[(size_t)((b*NN) + n0 + nl)*64 + c];
  }
  __syncthreads();
  int nl = threadIdx.x & 63;
  int og = __builtin_amdgcn_readfirstlane((int)(threadIdx.x >> 6) * 16);
  float z[16];
  #pragma unroll
  for (int m = 0; m < 16; m++) z[m] = 0.f;
  for (int c = 0; c < 64; c++){
    float yv = yt[nl][c];
    #pragma unroll
    for (int m = 0; m < 16; m++) z[m] = fmaf(yv, conv_w[(og+m)*64 + c], z[m]);
  }
  const float scbn = 1.f / sqrtf(1.f + 1e-5f);
  #pragma unroll
  for (int m = 0; m < 16; m++){
    int o = og + m;
    size_t oi = ((size_t)(b*64 + o))*NN + n0 + nl;
    out[oi] = fmaf(z[m] + conv_b[o], bn_g[o]*scbn, bn_b[o]) + x[oi];
  }
}

extern "C" void kernel_launch(void* const* d_in, const int* in_sizes, int n_in,
                              void* d_out, int out_size, void* d_ws, size_t ws_size,
                              hipStream_t stream){
  (void)in_sizes; (void)n_in; (void)out_size; (void)ws_size;
  const float* x       = (const float*)d_in[0];
  const float* W_heads = (const float*)d_in[1];
  const float* a_heads = (const float*)d_in[2];
  const float* W_out   = (const float*)d_in[3];
  const float* a_out   = (const float*)d_in[4];
  const float* conv_w  = (const float*)d_in[5];
  const float* conv_b  = (const float*)d_in[6];
  const float* bn_g    = (const float*)d_in[7];
  const float* bn_b    = (const float*)d_in[8];
  float* ws  = (float*)d_ws;
  float* out = (float*)d_out;

  float* hn   = ws + OFF_HN;
  float* sqv  = ws + OFF_SQV;
  int*   idxb = (int*)(ws + OFF_IDX);
  float* den1 = ws + OFF_DEN1;
  float* u1   = ws + OFF_U1;
  float* den2 = ws + OFF_DEN2;
  float* u2   = ws + OFF_U2;
  float* f11  = ws + OFF_F11;
  float* f21  = ws + OFF_F21;
  float* f12  = ws + OFF_F12;
  float* f22  = ws + OFF_F22;
  float* e1   = ws + OFF_E1;
  float* e2   = ws + OFF_E2;
  float* Wh1  = ws + OFF_WH1;
  float* hcat = ws + OFF_HCAT;
  float* Wh2  = ws + OFF_WH2;
  float* ytil = ws + OFF_YTIL;
  unsigned long long* cand = (unsigned long long*)(ws + OFF_CAND);

  k1_norm_wh<<<dim3(328), dim3(256), 0, stream>>>(x, W_heads, a_heads, hn, sqv, Wh1, f11, f21, ws);
  k2cand<<<dim3(16,16,4), dim3(256), 0, stream>>>(hn, sqv, cand);
  k2merge<<<dim3(64), dim3(256), 0, stream>>>(cand, f11, f21, idxb, e1, den1);
  k4b_u1<<<dim3(256), dim3(256), 0, stream>>>(den1, Wh1, u1);
  k5_hp1<<<dim3(4096), dim3(256), 0, stream>>>(idxb, e1, den1, Wh1, u1, hcat);
  k7_wh2<<<dim3(16,16), dim3(256), 0, stream>>>(hcat, W_out, a_out, Wh2, f12, f22);
  k8_edge2<<<dim3(576), dim3(256), 0, stream>>>(idxb, f12, f22, e2, den2);
  k8b_u2<<<dim3(64), dim3(256), 0, stream>>>(den2, Wh2, u2);
  k9_hp2<<<dim3(4096), dim3(256), 0, stream>>>(idxb, e2, den2, Wh2, u2, ytil);
  k11_conv<<<dim3(16,16), dim3(256), 0, stream>>>(ytil, conv_w, conv_b, bn_g, bn_b, x, out);
}